// Round 1
// baseline (650.264 us; speedup 1.0000x reference)
//
#include <hip/hip_runtime.h>
#include <math.h>

#define DIM 128
#define CHUNK 8            // nodes per stream per round (deeper in-flight: 8 x 16B/lane)
#define STREAMS 8          // half-wave node-streams per 256-thread block
#define ROUND (STREAMS * CHUNK)

typedef float v4f __attribute__((ext_vector_type(4)));

// Kernel A: segment boundaries. seg[g] = first index i with batch[i] >= g,
// for g in [0, ng]. One coalesced 4 MB read; removes the per-block binary
// search (~40 dependent global loads of serial latency) from the main kernel.
__global__ __launch_bounds__(256) void seg_bounds_kernel(
    const int* __restrict__ batch, int* __restrict__ seg, int n, int ng)
{
    const int i = blockIdx.x * blockDim.x + threadIdx.x;
    if (i > n) return;
    const int prev = (i == 0) ? -1 : batch[i - 1];
    const int cur  = (i == n) ? ng : batch[i];
    for (int g = prev + 1; g <= cur; ++g) seg[g] = i;
}

// Kernel B: one block per graph. 256 threads = 4 waves = 8 half-wave streams.
// Each 32-lane half processes CHUNK nodes/round, prefetching the next round's
// CHUNK (regular cached loads — NT reads bypassed L2 and appeared to cap
// effective read BW at ~1.65 TB/s). 8 interleaved shuffle-reduction trees,
// one online-softmax rescale per round.
__global__ __launch_bounds__(256) void attnpool_kernel(
    const float* __restrict__ x, const float* __restrict__ q,
    const int* __restrict__ seg, float* __restrict__ out)
{
    const int g    = blockIdx.x;
    const int tid  = threadIdx.x;
    const int wave = tid >> 6;
    const int lane = tid & 63;
    const int half = lane >> 5;   // 0 or 1
    const int hl   = lane & 31;   // lane within half
    const int sid  = wave * 2 + half;

    const int lo = seg[g];
    const int hi = seg[g + 1];

    // per-lane query fragment (dims hl*4 .. hl*4+3)
    const float4 qf = *(const float4*)(q + hl * 4);

    float  m = -INFINITY;
    float  l = 0.f;
    float4 o = make_float4(0.f, 0.f, 0.f, 0.f);

    const int i0 = lo + sid;          // this stream's first node
    const v4f zz = (v4f)0.f;
    const float* xb = x + hl * 4;

    v4f cur[CHUNK];
    #pragma unroll
    for (int j = 0; j < CHUNK; ++j) {
        const int ii = i0 + j * STREAMS;
        cur[j] = (ii < hi) ? *(const v4f*)(xb + (size_t)ii * DIM) : zz;
    }

    for (int base = i0; base < hi; base += ROUND) {
        // prefetch next round (loads stay in flight through the butterflies)
        v4f nxt[CHUNK];
        #pragma unroll
        for (int j = 0; j < CHUNK; ++j) {
            const int ii = base + ROUND + j * STREAMS;
            nxt[j] = (ii < hi) ? *(const v4f*)(xb + (size_t)ii * DIM) : zz;
        }

        // CHUNK independent dot partials
        float s[CHUNK];
        #pragma unroll
        for (int j = 0; j < CHUNK; ++j)
            s[j] = cur[j].x * qf.x + cur[j].y * qf.y + cur[j].z * qf.z + cur[j].w * qf.w;

        // CHUNK interleaved butterfly trees over the 32-lane half (masks <=16)
        #pragma unroll
        for (int d = 16; d >= 1; d >>= 1) {
            #pragma unroll
            for (int j = 0; j < CHUNK; ++j)
                s[j] += __shfl_xor(s[j], d);
        }

        // invalidate tail entries (half-uniform condition)
        #pragma unroll
        for (int j = 0; j < CHUNK; ++j)
            if (base + j * STREAMS >= hi) s[j] = -INFINITY;

        float smax = s[0];
        #pragma unroll
        for (int j = 1; j < CHUNK; ++j) smax = fmaxf(smax, s[j]);

        if (smax > m) {   // one rescale per round; m=-inf first time -> exp=0
            const float a = __expf(m - smax);
            l *= a;
            o.x *= a; o.y *= a; o.z *= a; o.w *= a;
            m = smax;
        }

        #pragma unroll
        for (int j = 0; j < CHUNK; ++j) {
            const float p = (base + j * STREAMS < hi) ? __expf(s[j] - m) : 0.f;
            l += p;
            o.x += p * cur[j].x; o.y += p * cur[j].y;
            o.z += p * cur[j].z; o.w += p * cur[j].w;
        }

        #pragma unroll
        for (int j = 0; j < CHUNK; ++j) cur[j] = nxt[j];
    }

    // merge the 8 partial online-softmax states through LDS
    __shared__ float sm_m[STREAMS];
    __shared__ float sm_l[STREAMS];
    __shared__ float sm_o[STREAMS * DIM];
    if (hl == 0) { sm_m[sid] = m; sm_l[sid] = l; }
    *(float4*)(sm_o + sid * DIM + hl * 4) = o;
    __syncthreads();

    if (tid < DIM) {
        float M = -INFINITY;
        #pragma unroll
        for (int h = 0; h < STREAMS; ++h)
            if (sm_l[h] > 0.f && sm_m[h] > M) M = sm_m[h];
        float L = 0.f, O = 0.f;
        #pragma unroll
        for (int h = 0; h < STREAMS; ++h) {
            if (sm_l[h] > 0.f) {
                const float c = __expf(sm_m[h] - M);
                L += c * sm_l[h];
                O += c * sm_o[h * DIM + tid];
            }
        }
        // empty segment -> L==0 -> write 0 (matches segment_sum identity)
        __builtin_nontemporal_store((L > 0.f) ? (O / L) : 0.f, out + (size_t)g * DIM + tid);
    }
}

extern "C" void kernel_launch(void* const* d_in, const int* in_sizes, int n_in,
                              void* d_out, int out_size, void* d_ws, size_t ws_size,
                              hipStream_t stream) {
    const float* x     = (const float*)d_in[0];
    const float* q     = (const float*)d_in[1];
    const int*   batch = (const int*)d_in[2];
    float*       out   = (float*)d_out;
    const int n          = in_sizes[0] / DIM;   // 1,000,000
    const int num_graphs = out_size / DIM;      // 4096

    int* seg = (int*)d_ws;                      // (num_graphs + 1) ints
    const int sb = (n + 1 + 255) / 256;
    seg_bounds_kernel<<<sb, 256, 0, stream>>>(batch, seg, n, num_graphs);
    attnpool_kernel<<<num_graphs, 256, 0, stream>>>(x, q, seg, out);
}